// Round 15
// baseline (164.487 us; speedup 1.0000x reference)
//
#include <hip/hip_runtime.h>
#include <hip/hip_bf16.h>
#include <math.h>

typedef __attribute__((ext_vector_type(8))) short short8;  // 8 bf16 = 4 VGPRs
typedef __attribute__((ext_vector_type(4))) float f32x4;

// Problem dims
#define D0n 8
#define D1n 12
#define D2n 6
#define Ln 2000
#define An 21
#define KPn 8
#define Un 48
#define PPn 1993              // L - k + 1
#define Bn 576                // D0*D1*D2
#define S_SIZE 4608           // (D0*D1) * U
#define R_SIZE 8064

// Conv tiling: 512 threads = 8 waves, each wave 32 positions x 48 u (the
// proven 64-VGPR shape). ONE 256-pos tile per block, single X buffer.
// LDS 41.5KB -> 3 resident blocks/CU = 24 waves/CU; grid (8,576) = 18/CU
// queued for stagger: stage(A) || compute(B) || drain(C).
#define BPn 256
#define NBX 8
#define XROWS 264              // 256 + 8 halo
#define XS_BYTES (XROWS * 64)  // 16896
#define RB_BYTES (384 * 64)    // 24576
#define BOFF XS_BYTES

// XOR swizzle within each 512B (8-row) group; bijective involution,
// 16B-granular. Writer and reader both apply it.
__device__ __forceinline__ int swz(int b) { return b ^ ((b >> 2) & 0x70); }

__device__ __forceinline__ unsigned int fkey(float f) {
    unsigned int u = __float_as_uint(f);
    return (u & 0x80000000u) ? ~u : (u | 0x80000000u);
}
__device__ __forceinline__ float funkey(unsigned int k) {
    return __uint_as_float((k & 0x80000000u) ? (k ^ 0x80000000u) : ~k);
}
__device__ __forceinline__ unsigned short f2bf(float v) {
    unsigned int b = __float_as_uint(v);
    return (unsigned short)((b + 0x7FFFu + ((b >> 16) & 1u)) >> 16);  // RNE
}

#define GLOAD_LDS16(g, l)                                                     \
    __builtin_amdgcn_global_load_lds(                                          \
        (const __attribute__((address_space(1))) void*)(g),                    \
        (__attribute__((address_space(3))) void*)(l), 16, 0, 0)

// Kernel 1: zero S-keys; R = log(max(softmax(P_logit)/Q, eps)) -> fp32 to
// d_out + bf16 padded(21->32, pad cols ZERO — keystone: makes X-pad garbage
// harmless) pre-swizzled copy to ws.
__global__ void k_profile(const float* __restrict__ P_logit,
                          const float* __restrict__ Q,
                          float* __restrict__ Rout,
                          unsigned short* __restrict__ Rb,
                          unsigned int* __restrict__ Skey) {
    int t = blockIdx.x * blockDim.x + threadIdx.x;
    if (t < S_SIZE) Skey[t] = 0u;
    if (t >= KPn * Un) return;
    int kp = t / Un, u = t % Un;
    const float* pl = P_logit + kp * (An * Un) + u;
    float v[An];
    float m = -INFINITY;
#pragma unroll
    for (int a = 0; a < An; ++a) { v[a] = pl[a * Un]; m = fmaxf(m, v[a]); }
    float s = 0.f;
#pragma unroll
    for (int a = 0; a < An; ++a) { v[a] = expf(v[a] - m); s += v[a]; }
    float inv = 1.f / s;
    int rowp = kp * Un + u;
#pragma unroll
    for (int a = 0; a < An; ++a) {
        float r = logf(fmaxf(v[a] * inv / Q[a], 1e-6f));
        Rout[(kp * An + a) * Un + u] = r;
        Rb[swz(rowp * 64 + a * 2) >> 1] = f2bf(r);
    }
#pragma unroll
    for (int a = An; a < 32; ++a) Rb[swz(rowp * 64 + a * 2) >> 1] = 0;
}

// Scatter one flat float4 (4 consecutive X elems) into swizzled bf16 LDS.
// Writes only element bytes 0..41 of each row (a < 21) -- disjoint from the
// pad-zero writes (bytes 42..63).
__device__ __forceinline__ void xwrite4(char* xbase, int idx, f32x4 g) {
    int fi = idx * 4;
    int row = fi / An;          // magic-mul
    int a = fi - row * An;
#pragma unroll
    for (int e = 0; e < 4; ++e) {
        *(unsigned short*)(xbase + swz(row * 64 + a * 2)) = f2bf(g[e]);
        ++a;
        if (a == An) { a = 0; ++row; }
    }
}

// Kernel 2: one 256-pos tile / block, 8 waves x 32 pos, ONE barrier,
// per-wave atomics, regular stores. launch_bounds(512,6) caps VGPR at 85
// (body measured ~64 in the R6 profile of this exact shape -> no spill),
// guaranteeing the 3-block/CU residency the LDS size allows.
__global__ __launch_bounds__(512, 6) void k_conv(
        const float* __restrict__ X,
        const unsigned short* __restrict__ Rb,
        float* __restrict__ Z,
        unsigned int* __restrict__ Skey) {
    __shared__ char smem[XS_BYTES + RB_BYTES];
    const int b = blockIdx.y;
    const int base_p = blockIdx.x * BPn;
    const int t = threadIdx.x;
    const int l = t & 63;
    const int w = t >> 6;
    const int lr = l & 15;
    const int ls = l >> 4;
    const int pw = w * 32;

    // 1) Coalesced X loads (flat float4; lane-contiguous).
    const int rows = min(XROWS, Ln - base_p);   // 264, or 208 at bx=7
    const int n4 = rows * An / 4;               // 1386 or 1092 (integral)
    f32x4 g[3];
    {
        const f32x4* src = (const f32x4*)(X + ((size_t)b * Ln + base_p) * An);
#pragma unroll
        for (int i = 0; i < 3; ++i) {
            int idx = t + i * 512;
            g[i] = (idx < n4) ? src[idx] : (f32x4){0.f, 0.f, 0.f, 0.f};
        }
    }
    // 2) Async R stage (linear DMA of pre-swizzled ws copy).
    {
        const char* src = (const char*)Rb;
        char* dst = smem + BOFF;
#pragma unroll
        for (int i = 0; i < RB_BYTES / 16 / 512; ++i) {  // 3
            int idx = t + i * 512;
            GLOAD_LDS16(src + idx * 16, dst + idx * 16);
        }
    }
    // 3) Zero X pad bytes 42..63 of every row (elems 21..31 must be FINITE:
    //    they multiply R's zero pad cols; stale LDS could be NaN-patterned).
    for (int row = t; row < XROWS; row += 512) {
        *(unsigned short*)(smem + swz(row * 64 + 42)) = 0;
#pragma unroll
        for (int j = 0; j < 5; ++j)
            *(unsigned int*)(smem + swz(row * 64 + 44 + 4 * j)) = 0u;
    }
    // 4) Zero tail rows (bx=7 only: rows 208..263). They feed only masked
    //    p >= PPn outputs, but must be finite.
    if (rows < XROWS) {
        uint4 z4 = {0u, 0u, 0u, 0u};
        for (int j = t; j < (XROWS - rows) * 4; j += 512)
            *(uint4*)(smem + swz((rows + (j >> 2)) * 64 + (j & 3) * 16)) = z4;
    }
    // 5) Convert + scatter-write X into LDS.
#pragma unroll
    for (int i = 0; i < 3; ++i) {
        int idx = t + i * 512;
        if (idx < n4) xwrite4((char*)smem, idx, g[i]);
    }
    __syncthreads();  // the ONLY barrier: publishes X + drains R DMA

    // q-loop (R8's proven shape): per q: 3 R-frags + 2 X-frags -> 6 MFMA.
    f32x4 acc[3][2];
#pragma unroll
    for (int nu = 0; nu < 3; ++nu)
#pragma unroll
        for (int np = 0; np < 2; ++np) acc[nu][np] = (f32x4){0.f, 0.f, 0.f, 0.f};

#pragma unroll
    for (int q = 0; q < KPn; ++q) {
        const int rr = q * Un + lr;
        short8 rf0 = *(const short8*)(smem + BOFF + swz(rr * 64 + ls * 16));
        short8 rf1 = *(const short8*)(smem + BOFF + swz((rr + 16) * 64 + ls * 16));
        short8 rf2 = *(const short8*)(smem + BOFF + swz((rr + 32) * 64 + ls * 16));
        const int xr = pw + q + lr;
        short8 xf0 = *(const short8*)(smem + swz(xr * 64 + ls * 16));
        short8 xf1 = *(const short8*)(smem + swz((xr + 16) * 64 + ls * 16));
        acc[0][0] = __builtin_amdgcn_mfma_f32_16x16x32_bf16(rf0, xf0, acc[0][0], 0, 0, 0);
        acc[0][1] = __builtin_amdgcn_mfma_f32_16x16x32_bf16(rf0, xf1, acc[0][1], 0, 0, 0);
        acc[1][0] = __builtin_amdgcn_mfma_f32_16x16x32_bf16(rf1, xf0, acc[1][0], 0, 0, 0);
        acc[1][1] = __builtin_amdgcn_mfma_f32_16x16x32_bf16(rf1, xf1, acc[1][1], 0, 0, 0);
        acc[2][0] = __builtin_amdgcn_mfma_f32_16x16x32_bf16(rf2, xf0, acc[2][0], 0, 0, 0);
        acc[2][1] = __builtin_amdgcn_mfma_f32_16x16x32_bf16(rf2, xf1, acc[2][1], 0, 0, 0);
    }

    // Z stores + per-lane max. Lane owns Z[p=base+pw+np*16+lr][u=nu*16+ls*4..+3].
    float smax[3][4];
#pragma unroll
    for (int nu = 0; nu < 3; ++nu)
#pragma unroll
        for (int r = 0; r < 4; ++r) smax[nu][r] = -INFINITY;

    float* Zb = Z + (size_t)b * PPn * Un;
#pragma unroll
    for (int np = 0; np < 2; ++np) {
        int p = base_p + pw + np * 16 + lr;
        if (p < PPn) {
            float* zp = Zb + (size_t)p * Un + ls * 4;
#pragma unroll
            for (int nu = 0; nu < 3; ++nu) {
                *(f32x4*)(zp + nu * 16) = acc[nu][np];
#pragma unroll
                for (int r = 0; r < 4; ++r)
                    smax[nu][r] = fmaxf(smax[nu][r], acc[nu][np][r]);
            }
        }
    }

    // Per-wave S reduction over the 16 position-lanes, then direct atomics.
    const int grp = b / D2n;
#pragma unroll
    for (int nu = 0; nu < 3; ++nu)
#pragma unroll
        for (int r = 0; r < 4; ++r) {
            float v = smax[nu][r];
            v = fmaxf(v, __shfl_xor(v, 1));
            v = fmaxf(v, __shfl_xor(v, 2));
            v = fmaxf(v, __shfl_xor(v, 4));
            v = fmaxf(v, __shfl_xor(v, 8));
            if (lr == 0)
                atomicMax(&Skey[grp * Un + nu * 16 + ls * 4 + r], fkey(v));
        }
}

// Kernel 3: decode monotone keys -> float S, in place.
__global__ void k_decode(unsigned int* __restrict__ Skey) {
    int t = blockIdx.x * blockDim.x + threadIdx.x;
    if (t < S_SIZE) {
        float f = funkey(Skey[t]);
        ((float*)Skey)[t] = f;
    }
}

extern "C" void kernel_launch(void* const* d_in, const int* in_sizes, int n_in,
                              void* d_out, int out_size, void* d_ws, size_t ws_size,
                              hipStream_t stream) {
    const float* X = (const float*)d_in[0];
    const float* P_logit = (const float*)d_in[1];
    const float* Q = (const float*)d_in[2];

    float* S = (float*)d_out;
    float* Rout = S + S_SIZE;
    float* Z = Rout + R_SIZE;
    unsigned short* Rb = (unsigned short*)d_ws;  // 24576 bytes of ws

    k_profile<<<(S_SIZE + 63) / 64, 64, 0, stream>>>(P_logit, Q, Rout, Rb,
                                                     (unsigned int*)d_out);

    dim3 grid(NBX, Bn);  // 8 x 256 positions = 2048 >= 1993
    k_conv<<<grid, 512, 0, stream>>>(X, Rb, Z, (unsigned int*)d_out);

    k_decode<<<(S_SIZE + 255) / 256, 256, 0, stream>>>((unsigned int*)d_out);
}

// Round 16
// 82.823 us; speedup vs baseline: 1.9860x; 1.9860x over previous
//
#include <hip/hip_runtime.h>
#include <math.h>

typedef __attribute__((ext_vector_type(8))) short short8;  // 8 bf16 = 4 VGPRs
typedef __attribute__((ext_vector_type(4))) float f32x4;

// Problem dims
#define D0n 8
#define D1n 12
#define D2n 6
#define Ln 2000
#define An 21
#define KPn 8
#define Un 48
#define PPn 1993              // L - k + 1
#define Bn 576                // D0*D1*D2
#define S_SIZE 4608           // (D0*D1) * U
#define R_SIZE 8064

// Conv tiling: 512 threads = 8 waves; wave = 32 positions x 48 u.
// Block: 2 tiles of 256 positions; grid (4, 576) = 2304 blocks = 9/CU exact.
#define BPn 256
#define TILES 2
#define NBX 4
#define XROWS 264              // 256 + halo, even
#define XBUF_BYTES (XROWS * 64)  // 16896
#define RB_BYTES (384 * 64)    // 24576
#define BOFF (2 * XBUF_BYTES)
#define RED_OFF (BOFF + RB_BYTES)

// XOR swizzle within each 512B (8-row) group; bijective, 16B-granular.
__device__ __forceinline__ int swz(int b) { return b ^ ((b >> 2) & 0x70); }

__device__ __forceinline__ unsigned int fkey(float f) {
    unsigned int u = __float_as_uint(f);
    return (u & 0x80000000u) ? ~u : (u | 0x80000000u);
}
__device__ __forceinline__ float funkey(unsigned int k) {
    return __uint_as_float((k & 0x80000000u) ? (k ^ 0x80000000u) : ~k);
}
__device__ __forceinline__ unsigned short f2bf(float v) {
    unsigned int b = __float_as_uint(v);
    return (unsigned short)((b + 0x7FFFu + ((b >> 16) & 1u)) >> 16);  // RNE
}

#define GLOAD_LDS16(g, l)                                                     \
    __builtin_amdgcn_global_load_lds(                                          \
        (const __attribute__((address_space(1))) void*)(g),                    \
        (__attribute__((address_space(3))) void*)(l), 16, 0, 0)

// lgkm-only wait + raw barrier: do NOT drain vmcnt (Z-stores stay in flight
// across tile boundaries; they have no readers).
#define TILE_BARRIER()                                                        \
    do {                                                                      \
        asm volatile("s_waitcnt lgkmcnt(0)" ::: "memory");                    \
        __builtin_amdgcn_s_barrier();                                         \
        asm volatile("" ::: "memory");                                        \
    } while (0)

// Kernel 1: zero S-keys; R = log(max(softmax(P_logit)/Q, eps)) -> fp32 to
// d_out + bf16 padded(21->32, pad cols ZERO) pre-swizzled copy to ws (row =
// q*48+u, 64B rows) staged verbatim by k_conv via global_load_lds.
__global__ void k_profile(const float* __restrict__ P_logit,
                          const float* __restrict__ Q,
                          float* __restrict__ Rout,
                          unsigned short* __restrict__ Rb,
                          unsigned int* __restrict__ Skey) {
    int t = blockIdx.x * blockDim.x + threadIdx.x;
    if (t < S_SIZE) Skey[t] = 0u;
    if (t >= KPn * Un) return;
    int kp = t / Un, u = t % Un;
    const float* pl = P_logit + kp * (An * Un) + u;
    float v[An];
    float m = -INFINITY;
#pragma unroll
    for (int a = 0; a < An; ++a) { v[a] = pl[a * Un]; m = fmaxf(m, v[a]); }
    float s = 0.f;
#pragma unroll
    for (int a = 0; a < An; ++a) { v[a] = expf(v[a] - m); s += v[a]; }
    float inv = 1.f / s;
    int rowp = kp * Un + u;
#pragma unroll
    for (int a = 0; a < An; ++a) {
        float r = logf(fmaxf(v[a] * inv / Q[a], 1e-6f));
        Rout[(kp * An + a) * Un + u] = r;
        Rb[swz(rowp * 64 + a * 2) >> 1] = f2bf(r);
    }
#pragma unroll
    for (int a = An; a < 32; ++a) Rb[swz(rowp * 64 + a * 2) >> 1] = 0;
}

// Convert one staged float4 (4 consecutive flat X elems) to swizzled bf16 LDS.
__device__ __forceinline__ void xwrite4(char* xbase, int idx, f32x4 g) {
    int fi = idx * 4;
    int row = fi / An;
    int a = fi - row * An;
#pragma unroll
    for (int e = 0; e < 4; ++e) {
        *(unsigned short*)(xbase + swz(row * 64 + a * 2)) = f2bf(g[e]);
        ++a;
        if (a == An) { a = 0; ++row; }
    }
}

__device__ __forceinline__ void xload(const float* __restrict__ X, int b,
                                      int tp0, int t, f32x4 g[3], int& n4) {
    int rows = min(XROWS, Ln - tp0);
    n4 = rows * An / 4;  // rows in {264, 208} -> always divisible by 4
    const f32x4* src = (const f32x4*)(X + ((size_t)b * Ln + tp0) * An);
#pragma unroll
    for (int i = 0; i < 3; ++i) {
        int idx = t + i * 512;
        g[i] = (idx < n4) ? src[idx] : (f32x4){0.f, 0.f, 0.f, 0.f};
    }
}

__device__ __forceinline__ void xstore(char* xbase, int t, const f32x4 g[3],
                                       int n4) {
#pragma unroll
    for (int i = 0; i < 3; ++i) {
        int idx = t + i * 512;
        if (idx < n4) xwrite4(xbase, idx, g[i]);
    }
}

// q-loop: A-operand = R rows (u axis), B-operand = X rows (positions).
__device__ __forceinline__ void qloop8(const char* smem, const char* xb,
                                       int lr, int ls, int pw,
                                       f32x4 acc[3][2]) {
#pragma unroll
    for (int q = 0; q < KPn; ++q) {
        const int rr = q * Un + lr;
        short8 rf0 = *(const short8*)(smem + BOFF + swz(rr * 64 + ls * 16));
        short8 rf1 = *(const short8*)(smem + BOFF + swz((rr + 16) * 64 + ls * 16));
        short8 rf2 = *(const short8*)(smem + BOFF + swz((rr + 32) * 64 + ls * 16));
        const int xr = pw + q + lr;
        short8 xf0 = *(const short8*)(xb + swz(xr * 64 + ls * 16));
        short8 xf1 = *(const short8*)(xb + swz((xr + 16) * 64 + ls * 16));
        acc[0][0] = __builtin_amdgcn_mfma_f32_16x16x32_bf16(rf0, xf0, acc[0][0], 0, 0, 0);
        acc[0][1] = __builtin_amdgcn_mfma_f32_16x16x32_bf16(rf0, xf1, acc[0][1], 0, 0, 0);
        acc[1][0] = __builtin_amdgcn_mfma_f32_16x16x32_bf16(rf1, xf0, acc[1][0], 0, 0, 0);
        acc[1][1] = __builtin_amdgcn_mfma_f32_16x16x32_bf16(rf1, xf1, acc[1][1], 0, 0, 0);
        acc[2][0] = __builtin_amdgcn_mfma_f32_16x16x32_bf16(rf2, xf0, acc[2][0], 0, 0, 0);
        acc[2][1] = __builtin_amdgcn_mfma_f32_16x16x32_bf16(rf2, xf1, acc[2][1], 0, 0, 0);
    }
}

// Z stores: lane owns Z[p = tp0+pw+np*16+lr][u = ls*4 + nu*16 .. +3].
__device__ __forceinline__ void store_tile(float* __restrict__ Z, int b,
                                           int tp0, int pw, int lr, int ls,
                                           const f32x4 acc[3][2],
                                           float smax[3][4]) {
#pragma unroll
    for (int np = 0; np < 2; ++np) {
        int p = tp0 + pw + np * 16 + lr;
        if (p < PPn) {
            float* zp = Z + ((size_t)b * PPn + p) * Un + ls * 4;
#pragma unroll
            for (int nu = 0; nu < 3; ++nu) {
                *(f32x4*)(zp + nu * 16) = acc[nu][np];
#pragma unroll
                for (int r = 0; r < 4; ++r)
                    smax[nu][r] = fmaxf(smax[nu][r], acc[nu][np][r]);
            }
        }
    }
}

__global__ __launch_bounds__(512, 4) void k_conv(
        const float* __restrict__ X,
        const unsigned short* __restrict__ Rb,
        float* __restrict__ Z,
        unsigned int* __restrict__ Skey) {
    __shared__ char smem[RED_OFF + 8 * Un * 4];
    const int b = blockIdx.y;
    const int base_p = blockIdx.x * (TILES * BPn);
    const int t = threadIdx.x;
    const int w = t >> 6;
    const int l = t & 63;
    const int lr = l & 15;
    const int ls = l >> 4;
    const int pw = w * 32;

    // ---- Prologue ----
    {   // Stage B (async; ws copy is linear bf16+padded+swizzled).
        const char* src = (const char*)Rb;
        char* dst = smem + BOFF;
#pragma unroll
        for (int i = 0; i < RB_BYTES / 16 / 512; ++i) {  // 3
            int idx = t + i * 512;
            GLOAD_LDS16(src + idx * 16, dst + idx * 16);
        }
    }
    {   // Zero-fill BOTH X buffers (pad columns stay zero forever).
        uint4 z4 = {0u, 0u, 0u, 0u};
        uint4* xs = (uint4*)smem;
        for (int i = t; i < 2 * XBUF_BYTES / 16; i += 512) xs[i] = z4;
    }
    f32x4 g[3];
    int n4;
    xload(X, b, base_p, t, g, n4);
    __syncthreads();  // full drain once: gload_lds B-stage + zero-fill
    xstore((char*)smem, t, g, n4);
    TILE_BARRIER();   // buf0 published (lgkm only)

    float smax[3][4];
#pragma unroll
    for (int nu = 0; nu < 3; ++nu)
#pragma unroll
        for (int r = 0; r < 4; ++r) smax[nu][r] = -INFINITY;

    f32x4 acc[3][2];

    // ---- Tile 0 ----
    xload(X, b, base_p + BPn, t, g, n4);  // prefetch tile 1
#pragma unroll
    for (int nu = 0; nu < 3; ++nu)
#pragma unroll
        for (int np = 0; np < 2; ++np) acc[nu][np] = (f32x4){0.f, 0.f, 0.f, 0.f};
    qloop8((const char*)smem, (const char*)smem, lr, ls, pw, acc);
    xstore((char*)smem + XBUF_BYTES, t, g, n4);   // stage tile 1 -> buf1
    store_tile(Z, b, base_p, pw, lr, ls, acc, smax);
    TILE_BARRIER();   // buf1 published; Z-stores remain in flight

    // ---- Tile 1 ----
#pragma unroll
    for (int nu = 0; nu < 3; ++nu)
#pragma unroll
        for (int np = 0; np < 2; ++np) acc[nu][np] = (f32x4){0.f, 0.f, 0.f, 0.f};
    qloop8((const char*)smem, (const char*)smem + XBUF_BYTES, lr, ls, pw, acc);
    store_tile(Z, b, base_p + BPn, pw, lr, ls, acc, smax);

    // ---- S reduction: max over positions (lr lanes), then waves ----
    float* red = (float*)(smem + RED_OFF);
#pragma unroll
    for (int nu = 0; nu < 3; ++nu)
#pragma unroll
        for (int r = 0; r < 4; ++r) {
            float v = smax[nu][r];
            v = fmaxf(v, __shfl_xor(v, 1));
            v = fmaxf(v, __shfl_xor(v, 2));
            v = fmaxf(v, __shfl_xor(v, 4));
            v = fmaxf(v, __shfl_xor(v, 8));
            if (lr == 0) red[w * Un + nu * 16 + ls * 4 + r] = v;
        }
    __syncthreads();
    if (t < Un) {
        float m = -INFINITY;
#pragma unroll
        for (int wv = 0; wv < 8; ++wv) m = fmaxf(m, red[wv * Un + t]);
        atomicMax(&Skey[(b / D2n) * Un + t], fkey(m));
    }
}

// Kernel 3: decode monotone keys -> float S, in place.
__global__ void k_decode(unsigned int* __restrict__ Skey) {
    int t = blockIdx.x * blockDim.x + threadIdx.x;
    if (t < S_SIZE) {
        float f = funkey(Skey[t]);
        ((float*)Skey)[t] = f;
    }
}

extern "C" void kernel_launch(void* const* d_in, const int* in_sizes, int n_in,
                              void* d_out, int out_size, void* d_ws, size_t ws_size,
                              hipStream_t stream) {
    const float* X = (const float*)d_in[0];
    const float* P_logit = (const float*)d_in[1];
    const float* Q = (const float*)d_in[2];

    float* S = (float*)d_out;
    float* Rout = S + S_SIZE;
    float* Z = Rout + R_SIZE;
    unsigned short* Rb = (unsigned short*)d_ws;  // 24576 bytes of ws

    k_profile<<<(S_SIZE + 63) / 64, 64, 0, stream>>>(P_logit, Q, Rout, Rb,
                                                     (unsigned int*)d_out);

    dim3 grid(NBX, Bn);  // 4 x 2 tiles x 256 positions = 2048 >= 1993
    k_conv<<<grid, 512, 0, stream>>>(X, Rb, Z, (unsigned int*)d_out);

    k_decode<<<(S_SIZE + 255) / 256, 256, 0, stream>>>((unsigned int*)d_out);
}